// Round 4
// baseline (84.923 us; speedup 1.0000x reference)
//
#include <hip/hip_runtime.h>
#include <stdint.h>

#define EPS 1e-8f

constexpr int NROWS = 1024;  // rows of x and of y
constexpr int K     = 256;   // feature dim
constexpr int TILE  = 32;    // 32x32 output tile per 64-thread (1-wave) block
constexpr int KC    = 128;   // k-chunk staged in LDS (2 chunks total)

typedef __attribute__((address_space(3))) uint32_t* lds_ptr_t;
typedef const __attribute__((address_space(1))) uint32_t* glb_ptr_t;

// Fused Ruzicka kernel, 1 wave per block, straight-line schedule.
// Round-4 rationale: rounds 1-3 fought register spills (VGPR=256, scratch
// traffic visible as 60-370 MB WRITE_SIZE). This version is structurally
// spill-proof: single 32 KB LDS buffer, exactly two K-chunks, no double-buffer
// indexing, no unrolled chunk loop, bounded unroll (live ds_read results <= 32
// VGPR). The one WAR hand-off between chunks exposes ~700 cyc of DMA latency
// once (~0.3 us) -- accepted in exchange for a schedule the compiler cannot
// bloat. 32 KB LDS keeps 4 blocks/CU (all SIMDs fed); 64 KB dbuf would halve
// that.
// Carried forward (verified rounds 2-3: passed, SQ_LDS_BANK_CONFLICT = 0):
//  - global_load_lds width-16 staging (zero VGPR cost).
//  - Rule #21 swizzle: linear LDS dest + XOR-pre-swizzled global source
//    (granule g ^ cls, cls = (row>>2)&7) + same XOR on reads
//    (kk ^ (cls<<2)) -> 8 ty/tx broadcast groups hit 8 disjoint bank quads.
//  - Fused row sums: global-read prologue (hides chunk-0 DMA latency),
//    distributed via __shfl in the epilogue. No workspace use.
__global__ __launch_bounds__(64) void ruzicka_fused(const float* __restrict__ x,
                                                    const float* __restrict__ y,
                                                    float* __restrict__ out) {
    __shared__ __align__(16) float buf[64 * KC];  // 32 KB: rows 0..31 x-tile, 32..63 y-tile

    const int tid = threadIdx.x;   // 0..63
    const int tx  = tid & 7;       // output col group (y rows)
    const int ty  = tid >> 3;      // output row group (x rows)
    const int g   = tid & 31;      // staging granule (16B) within a 512B row
    const int r2  = tid >> 5;      // staging row parity (0..1)
    const int rowBase = blockIdx.y * TILE;
    const int colBase = blockIdx.x * TILE;

    // Stage one 128-wide k-chunk: 32 global_load_lds, instr i moves 2 rows x
    // 512B = 1024B linear LDS (lanes 0-31 -> row 2i, lanes 32-63 -> row 2i+1).
    // Source granule (g ^ cls) pre-applies the read-side swizzle; cls is
    // uniform per instr (both rows share row>>2).
    auto stage = [&](int kc) {
        #pragma unroll
        for (int i = 0; i < 16; ++i) {
            const int cls = (i >> 1) & 7;
            const float* gx = x + (size_t)(rowBase + 2 * i + r2) * K + kc + 4 * (g ^ cls);
            const float* gy = y + (size_t)(colBase + 2 * i + r2) * K + kc + 4 * (g ^ cls);
            __builtin_amdgcn_global_load_lds((glb_ptr_t)gx, (lds_ptr_t)&buf[i * 256],        16, 0, 0);
            __builtin_amdgcn_global_load_lds((glb_ptr_t)gy, (lds_ptr_t)&buf[(16 + i) * 256], 16, 0, 0);
        }
    };

    stage(0);  // chunk-0 DMA latency hides under the row-sum prologue

    // ---- prologue: full-K row sums, lane l -> tile row l ----
    const float* srow = (tid < 32) ? (x + (size_t)(rowBase + tid) * K)
                                   : (y + (size_t)(colBase + tid - 32) * K);
    float s = 0.0f;
    #pragma unroll 16
    for (int j = 0; j < K / 4; ++j) {
        const float4 v = ((const float4*)srow)[j];
        s += (v.x + v.y) + (v.z + v.w);
    }

    float num[4][4];
    #pragma unroll
    for (int r = 0; r < 4; ++r)
        #pragma unroll
        for (int c = 0; c < 4; ++c) num[r][c] = 0.0f;

    const int ka0 = ty << 2;
    const int kb0 = tx << 2;

    // compute one staged chunk from LDS (32 kk-steps, bounded unroll)
    auto compute = [&]() {
        #pragma unroll 2
        for (int kk = 0; kk < KC; kk += 4) {
            float4 a[4], b4[4];
            #pragma unroll
            for (int r = 0; r < 4; ++r)
                a[r] = *(const float4*)&buf[(ty * 4 + r) * KC + (kk ^ ka0)];
            #pragma unroll
            for (int c = 0; c < 4; ++c)
                b4[c] = *(const float4*)&buf[(32 + tx * 4 + c) * KC + (kk ^ kb0)];
            #pragma unroll
            for (int r = 0; r < 4; ++r)
                #pragma unroll
                for (int c = 0; c < 4; ++c) {
                    const float m0 = fminf(a[r].x, b4[c].x);
                    const float m1 = fminf(a[r].y, b4[c].y);
                    const float m2 = fminf(a[r].z, b4[c].z);
                    const float m3 = fminf(a[r].w, b4[c].w);
                    num[r][c] += (m0 + m1) + (m2 + m3);
                }
        }
    };

    // chunk 0: DMA landed (prologue consumed ~64 younger vmem ops, but DMA is
    // older; vmcnt(0) is then nearly free)
    asm volatile("s_waitcnt vmcnt(0)" ::: "memory");
    __builtin_amdgcn_sched_barrier(0);
    compute();

    // WAR hand-off: all chunk-0 ds_reads retired before the DMA overwrite
    asm volatile("s_waitcnt lgkmcnt(0)" ::: "memory");
    __builtin_amdgcn_sched_barrier(0);
    stage(KC);
    asm volatile("s_waitcnt vmcnt(0)" ::: "memory");
    __builtin_amdgcn_sched_barrier(0);
    compute();  // kk ranges over [0,KC) again; data is chunk 1's

    // ---- distribute row sums: lane (ty*4+r) holds Sx, lane (32+tx*4+c) holds Sy ----
    float sx[4], sy[4];
    #pragma unroll
    for (int r = 0; r < 4; ++r) sx[r] = __shfl(s, ty * 4 + r, 64);
    #pragma unroll
    for (int c = 0; c < 4; ++c) sy[c] = __shfl(s, 32 + tx * 4 + c, 64);

    #pragma unroll
    for (int r = 0; r < 4; ++r) {
        float4 o;
        float* op = &o.x;
        #pragma unroll
        for (int c = 0; c < 4; ++c) {
            const float n = num[r][c];
            op[c] = n / (sx[r] + sy[c] - n + EPS);  // den = Sx + Sy - num + EPS
        }
        *(float4*)&out[(size_t)(rowBase + ty * 4 + r) * NROWS + colBase + tx * 4] = o;
    }
}

extern "C" void kernel_launch(void* const* d_in, const int* in_sizes, int n_in,
                              void* d_out, int out_size, void* d_ws, size_t ws_size,
                              hipStream_t stream) {
    const float* x = (const float*)d_in[0];
    const float* y = (const float*)d_in[1];
    float* out = (float*)d_out;
    (void)d_ws; (void)ws_size;

    // 32x32 tiles -> 1024 one-wave blocks (4 blocks/CU across 256 CUs)
    ruzicka_fused<<<dim3(NROWS / TILE, NROWS / TILE), dim3(64), 0, stream>>>(x, y, out);
}